// Round 15
// baseline (560.842 us; speedup 1.0000x reference)
//
#include <hip/hip_runtime.h>
#include <hip/hip_bf16.h>

// Problem constants
#define B_  4
#define S_  1024
#define D_  1024
#define H_  16
#define DH_ 64
#define N_  64          // B*H
#define BS_ 4096        // B*S

// Workspace layout (bytes)
#define WS_CUR   0ull                        // 48 MB f32 cur[3][64][1024][64]
#define WS_XH    (WS_CUR + 48ull*1024*1024)  // 8 MB bf16 x_hi [4096][1024]
#define WS_XL    (WS_XH  +  8ull*1024*1024)  // 8 MB bf16 x_lo
#define WS_WCH   (WS_XL  +  8ull*1024*1024)  // 6 MB bf16 WcT_hi [3][1024][1024]
#define WS_WCL   (WS_WCH +  6ull*1024*1024)  // 6 MB bf16 WcT_lo
#define WS_MSK   (WS_WCL +  6ull*1024*1024)  // 1.5 MB masks
// overlays (safe by stream order):
#define WS_CTXH  WS_XH                       // attn output hi (x dead after proj)
#define WS_CTXL  WS_XL
#define WS_WOH   WS_WCH                      // Wo split (WcT dead after proj)
#define WS_WOL   (WS_WCH + 2ull*1024*1024)

typedef __attribute__((ext_vector_type(8))) short short8v;
typedef __attribute__((ext_vector_type(4))) float f32x4;

// round-to-nearest-even bf16 split: x == hi + lo + O(2^-18 |x|)
__device__ inline void bsplit(float x, unsigned short& h, unsigned short& l) {
    unsigned ux = __float_as_uint(x);
    unsigned rh = (ux + 0x7FFFu + ((ux >> 16) & 1u)) >> 16;
    h = (unsigned short)rh;
    float r = x - __uint_as_float(rh << 16);
    unsigned ur = __float_as_uint(r);
    l = (unsigned short)((ur + 0x7FFFu + ((ur >> 16) & 1u)) >> 16);
}

// ---------------------------------------------------------------------------
// k_prep: merged x-split (blocks 0..4095) + Wc transpose/split (4096..7167).
// ---------------------------------------------------------------------------
__global__ __launch_bounds__(256) void k_prep(
    const float* __restrict__ x,
    const float* __restrict__ Wq, const float* __restrict__ Wk, const float* __restrict__ Wv,
    const float* __restrict__ Wqi, const float* __restrict__ Wki, const float* __restrict__ Wvi,
    unsigned short* __restrict__ xh, unsigned short* __restrict__ xl,
    unsigned short* __restrict__ wch, unsigned short* __restrict__ wcl)
{
    int blk = blockIdx.x;
    int tid = threadIdx.x;

    if (blk < 4096) {
        int i = (blk * 256 + tid) * 4;
        float4 v = *reinterpret_cast<const float4*>(&x[i]);
        ushort4 h, l;
        bsplit(v.x, h.x, l.x);
        bsplit(v.y, h.y, l.y);
        bsplit(v.z, h.z, l.z);
        bsplit(v.w, h.w, l.w);
        *reinterpret_cast<ushort4*>(&xh[i]) = h;
        *reinterpret_cast<ushort4*>(&xl[i]) = l;
        return;
    }

    int q = blk - 4096;
    int z = q >> 10, hd = q & 1023;
    const float* W  = (z == 0) ? Wq  : (z == 1) ? Wk  : Wv;
    const float* Wi = (z == 0) ? Wqi : (z == 1) ? Wki : Wvi;
    int h = hd >> 6, d = hd & 63;

    __shared__ float ws[64];
    if (tid < 64) ws[tid] = Wi[d * 64 + tid];
    __syncthreads();

    const float* Wb = W + (size_t)h * 64 * 1024;
    float acc[4] = {0.f, 0.f, 0.f, 0.f};
    for (int j = 0; j < 64; j++) {
        float wv = ws[j];
        const float* row = Wb + (size_t)j * 1024;
        #pragma unroll
        for (int mi = 0; mi < 4; mi++)
            acc[mi] += row[tid + mi * 256] * wv;
    }
    unsigned short* oh = wch + (size_t)z * 1024 * 1024 + (size_t)hd * 1024;
    unsigned short* ol = wcl + (size_t)z * 1024 * 1024 + (size_t)hd * 1024;
    #pragma unroll
    for (int mi = 0; mi < 4; mi++) {
        unsigned short hh, ll;
        bsplit(acc[mi], hh, ll);
        oh[tid + mi * 256] = hh;
        ol[tid + mi * 256] = ll;
    }
}

// ---------------------------------------------------------------------------
// Split-bf16 MFMA GEMM: C[m][n] = sum_k A[m][k]*B[n][k]  (B n-major)
// v5 (proven rounds 10/13): global_load_lds staging, BK=64, single 64 KB
// buffer, XOR-swizzled global source + same XOR on ds_read, float4 epilogue.
// (v6 counted-vmcnt double-buffer REGRESSED — reverted.)
// ---------------------------------------------------------------------------
template<int OUT>
__global__ __launch_bounds__(512, 4) void k_mfma_gemm(
    const unsigned short* __restrict__ Ah, const unsigned short* __restrict__ Al,
    const unsigned short* __restrict__ Bh, const unsigned short* __restrict__ Bl,
    float* __restrict__ C, const float* __restrict__ bias)
{
    // 4 mats x 128 rows x 64 ushorts = 64 KB. mat m at m*8192 (ushorts).
    __shared__ __align__(16) unsigned short lds[4 * 128 * 64];

    int tid = threadIdx.x;
    int bx = blockIdx.x, by = blockIdx.y, bz = blockIdx.z;
    const unsigned short* Bhz = Bh + (size_t)bz * 1024 * 1024;
    const unsigned short* Blz = Bl + (size_t)bz * 1024 * 1024;
    int rb = bx * 128, cb = by * 128;

    int wid = tid >> 6, lane = tid & 63;
    int wr = wid >> 2, wc = wid & 3;          // 2x4 wave grid: 64-row x 32-col tiles
    int r15 = lane & 15, g = lane >> 4;

    int rowA = lane >> 3;          // 0..7, == row&7 within chunk
    int kpsw = ((lane & 7) ^ rowA) * 8;

    f32x4 acc[4][2];
    #pragma unroll
    for (int mt = 0; mt < 4; mt++)
        #pragma unroll
        for (int nt = 0; nt < 2; nt++)
            acc[mt][nt] = (f32x4){0.f, 0.f, 0.f, 0.f};

    #pragma unroll 1
    for (int t = 0; t < 16; t++) {
        int kb = t * 64;
        #pragma unroll
        for (int i = 0; i < 8; i++) {
            int q = wid * 8 + i;
            int mat = q >> 4, ch = q & 15;
            const unsigned short* gsrc = (mat == 0) ? Ah : (mat == 1) ? Al
                                        : (mat == 2) ? Bhz : Blz;
            int rowoff = (mat < 2) ? rb : cb;
            int row = ch * 8 + rowA;
            __builtin_amdgcn_global_load_lds(
                (const __attribute__((address_space(1))) void*)
                    (gsrc + (size_t)(rowoff + row) * 1024 + kb + kpsw),
                (__attribute__((address_space(3))) void*)(&lds[mat * 8192 + ch * 512]),
                16, 0, 0);
        }
        __syncthreads();   // drains vmcnt -> tile resident

        #pragma unroll
        for (int kk = 0; kk < 2; kk++) {
            short8v bh[2], bl[2];
            #pragma unroll
            for (int nt = 0; nt < 2; nt++) {
                int Crow = wc * 32 + nt * 16 + r15;
                int off = Crow * 64 + (((kk * 4 + g) ^ (Crow & 7)) * 8);
                bh[nt] = *reinterpret_cast<const short8v*>(&lds[2 * 8192 + off]);
                bl[nt] = *reinterpret_cast<const short8v*>(&lds[3 * 8192 + off]);
            }
            #pragma unroll
            for (int mt = 0; mt < 4; mt++) {
                int Arow = wr * 64 + mt * 16 + r15;
                int off = Arow * 64 + (((kk * 4 + g) ^ (Arow & 7)) * 8);
                short8v ah = *reinterpret_cast<const short8v*>(&lds[0 * 8192 + off]);
                short8v al = *reinterpret_cast<const short8v*>(&lds[1 * 8192 + off]);
                #pragma unroll
                for (int nt = 0; nt < 2; nt++) {
                    acc[mt][nt] = __builtin_amdgcn_mfma_f32_16x16x32_bf16(bh[nt], ah, acc[mt][nt], 0, 0, 0);
                    acc[mt][nt] = __builtin_amdgcn_mfma_f32_16x16x32_bf16(bl[nt], ah, acc[mt][nt], 0, 0, 0);
                    acc[mt][nt] = __builtin_amdgcn_mfma_f32_16x16x32_bf16(bh[nt], al, acc[mt][nt], 0, 0, 0);
                }
            }
        }
        __syncthreads();   // all waves done reading before next stage overwrites
    }

    if (OUT == 0) {
        float* out = C + (size_t)bz * 64 * 1024 * 64;
        int b = rb >> 10;
        #pragma unroll
        for (int nt = 0; nt < 2; nt++) {
            int col = cb + wc * 32 + nt * 16 + g * 4;   // hd base, 16B aligned
            int h = col >> 6, dd = col & 63;
            #pragma unroll
            for (int mt = 0; mt < 4; mt++) {
                int row = rb + wr * 64 + mt * 16 + r15; // b*1024 + s
                int s = row & 1023;
                f32x4 a = acc[mt][nt];
                *reinterpret_cast<float4*>(&out[(((size_t)(b * 16 + h)) * 1024 + s) * 64 + dd]) =
                    make_float4(a[0], a[1], a[2], a[3]);
            }
        }
    } else {
        #pragma unroll
        for (int nt = 0; nt < 2; nt++) {
            int col = cb + wc * 32 + nt * 16 + g * 4;
            float4 bv = *reinterpret_cast<const float4*>(&bias[col]);
            #pragma unroll
            for (int mt = 0; mt < 4; mt++) {
                int row = rb + wr * 64 + mt * 16 + r15;
                f32x4 a = acc[mt][nt];
                *reinterpret_cast<float4*>(&C[(size_t)row * 1024 + col]) =
                    make_float4(a[0] + bv.x, a[1] + bv.y, a[2] + bv.z, a[3] + bv.w);
            }
        }
    }
}

// ---------------------------------------------------------------------------
// Stage B: LIF scan v7 — TWO chains per wave (same l -> shared T table).
// Chain B's 16 ds_reads issue while chain A's tree/state executes and vice
// versa: wall per pair ~= max(2 x issue, chain latency) < 2 x 483 cyc.
// Per-chain arithmetic order identical to v3 -> bit-identical masks.
// Blocks 0..95: LIF pairs (l = bid/32, nA = 2*(bid%32), nB = nA+1).
// Blocks 96..607: Wo -> bf16 hi/lo split (hidden under the scan).
// ---------------------------------------------------------------------------
__global__ __launch_bounds__(64) void k_lif_wo(
    const float* __restrict__ curAll,
    const float* __restrict__ Wrq, const float* __restrict__ Wrk, const float* __restrict__ Wrv,
    const float* __restrict__ thq, const float* __restrict__ thk, const float* __restrict__ thv,
    unsigned long long* __restrict__ masks,
    const float* __restrict__ Wo, unsigned short* __restrict__ woh, unsigned short* __restrict__ wol)
{
    __shared__ float T[16 * 16 * 64];                  // 64 KB (shared by A,B)
    __shared__ __align__(16) float cbufA[2][4096];     // 32 KB
    __shared__ __align__(16) float cbufB[2][4096];     // 32 KB

    int bid = blockIdx.x;
    int d = threadIdx.x;

    if (bid >= 96) {
        // ---- Wo split: 512 blocks x 2048 floats
        int q = bid - 96;
        #pragma unroll
        for (int it = 0; it < 8; it++) {
            int i = q * 2048 + it * 256 + d * 4;
            float4 v = *reinterpret_cast<const float4*>(&Wo[i]);
            ushort4 h, l;
            bsplit(v.x, h.x, l.x);
            bsplit(v.y, h.y, l.y);
            bsplit(v.z, h.z, l.z);
            bsplit(v.w, h.w, l.w);
            *reinterpret_cast<ushort4*>(&woh[i]) = h;
            *reinterpret_cast<ushort4*>(&wol[i]) = l;
        }
        return;
    }

    int l = bid >> 5, q = bid & 31;
    int nA = q * 2, nB = q * 2 + 1;
    const float* W  = (l == 0) ? Wrq : (l == 1) ? Wrk : Wrv;
    const float* th = (l == 0) ? thq : (l == 1) ? thk : thv;
    const float* cbaseA = curAll + (((size_t)l * 64 + nA) * 1024) * 64;
    const float* cbaseB = curAll + (((size_t)l * 64 + nB) * 1024) * 64;
    unsigned long long* moutA = masks + ((size_t)l * 64 + nA) * 1024;
    unsigned long long* moutB = masks + ((size_t)l * 64 + nB) * 1024;

    // batch-0 staging for both chains; latency hides under the table build
    #pragma unroll
    for (int j = 0; j < 16; j++)
        __builtin_amdgcn_global_load_lds(
            (const __attribute__((address_space(1))) void*)(cbaseA + j * 256 + d * 4),
            (__attribute__((address_space(3))) void*)(&cbufA[0][j * 256]), 16, 0, 0);
    #pragma unroll
    for (int j = 0; j < 16; j++)
        __builtin_amdgcn_global_load_lds(
            (const __attribute__((address_space(1))) void*)(cbaseB + j * 256 + d * 4),
            (__attribute__((address_space(3))) void*)(&cbufB[0][j * 256]), 16, 0, 0);

    float theta = th[d];

    for (int g = 0; g < 16; g++) {
        float w0 = W[d * 64 + 4 * g + 0];
        float w1 = W[d * 64 + 4 * g + 1];
        float w2 = W[d * 64 + 4 * g + 2];
        float w3 = W[d * 64 + 4 * g + 3];
        #pragma unroll
        for (int c = 0; c < 16; c++) {
            float t = 0.f;
            if (c & 1) t += w0;
            if (c & 2) t += w1;
            if (c & 4) t += w2;
            if (c & 8) t += w3;
            T[g * 1024 + c * 64 + d] = t;
        }
    }
    __syncthreads();   // batch 0 (A+B) resident, 0 outstanding

    float vA = 0.f, refracA = 0.f, athrA = 1.0f;
    float vB = 0.f, refracB = 0.f, athrB = 1.0f;
    unsigned mloA = 0u, mhiA = 0u, mloB = 0u, mhiB = 0u;
    unsigned bufLoA = 0u, bufHiA = 0u, bufLoB = 0u, bufHiB = 0u;

    for (int b = 0; b < 16; b++) {
        // drain batch b's 32 loads (issued at top of b-1); allow 2 mask stores
        if (b) asm volatile("s_waitcnt vmcnt(2)" ::: "memory");
        if (b < 15) {
            const float* srcA = cbaseA + (size_t)(b + 1) * 4096;
            const float* srcB = cbaseB + (size_t)(b + 1) * 4096;
            float* dstA = cbufA[(b + 1) & 1];
            float* dstB = cbufB[(b + 1) & 1];
            #pragma unroll
            for (int j = 0; j < 16; j++)
                __builtin_amdgcn_global_load_lds(
                    (const __attribute__((address_space(1))) void*)(srcA + j * 256 + d * 4),
                    (__attribute__((address_space(3))) void*)(dstA + j * 256), 16, 0, 0);
            #pragma unroll
            for (int j = 0; j < 16; j++)
                __builtin_amdgcn_global_load_lds(
                    (const __attribute__((address_space(1))) void*)(srcB + j * 256 + d * 4),
                    (__attribute__((address_space(3))) void*)(dstB + j * 256), 16, 0, 0);
        }

        const float* cbA = cbufA[b & 1];
        const float* cbB = cbufB[b & 1];
        #pragma unroll 4
        for (int i = 0; i < 64; i++) {
            float curA = cbA[i * 64 + d];
            float curB = cbB[i * 64 + d];

            // issue BOTH chains' table reads up front (B's fly during A's VALU)
            float tA[16], tB[16];
            #pragma unroll
            for (int g = 0; g < 8; g++)
                tA[g] = T[g * 1024 + (int)(((mloA >> (4 * g)) & 15u) << 6) + d];
            #pragma unroll
            for (int g = 0; g < 8; g++)
                tA[8 + g] = T[(8 + g) * 1024 + (int)(((mhiA >> (4 * g)) & 15u) << 6) + d];
            #pragma unroll
            for (int g = 0; g < 8; g++)
                tB[g] = T[g * 1024 + (int)(((mloB >> (4 * g)) & 15u) << 6) + d];
            #pragma unroll
            for (int g = 0; g < 8; g++)
                tB[8 + g] = T[(8 + g) * 1024 + (int)(((mhiB >> (4 * g)) & 15u) << 6) + d];

            // ---- chain A
            #pragma unroll
            for (int k = 8; k >= 1; k >>= 1)
                #pragma unroll
                for (int j = 0; j < k; j++)
                    tA[j] = tA[j] + tA[j + k];
            float totalA = curA + tA[0];
            vA = 0.9f * vA + totalA;
            vA = (refracA <= 0.f) ? vA : 0.f;
            bool spA = (vA >= athrA);
            unsigned long long mA = __ballot(spA);
            mloA = (unsigned)mA;
            mhiA = (unsigned)(mA >> 32);
            bufLoA = (d == i) ? mloA : bufLoA;
            bufHiA = (d == i) ? mhiA : bufHiA;
            float smA = spA ? 1.f : 0.f;
            vA = spA ? 0.f : vA;
            refracA = fmaxf(refracA - 1.f, smA * 2.f);
            athrA = 0.95f * athrA + smA * theta;

            // ---- chain B
            #pragma unroll
            for (int k = 8; k >= 1; k >>= 1)
                #pragma unroll
                for (int j = 0; j < k; j++)
                    tB[j] = tB[j] + tB[j + k];
            float totalB = curB + tB[0];
            vB = 0.9f * vB + totalB;
            vB = (refracB <= 0.f) ? vB : 0.f;
            bool spB = (vB >= athrB);
            unsigned long long mB = __ballot(spB);
            mloB = (unsigned)mB;
            mhiB = (unsigned)(mB >> 32);
            bufLoB = (d == i) ? mloB : bufLoB;
            bufHiB = (d == i) ? mhiB : bufHiB;
            float smB = spB ? 1.f : 0.f;
            vB = spB ? 0.f : vB;
            refracB = fmaxf(refracB - 1.f, smB * 2.f);
            athrB = 0.95f * athrB + smB * theta;
        }
        moutA[b * 64 + d] = ((unsigned long long)bufHiA << 32) | bufLoA;
        moutB[b * 64 + d] = ((unsigned long long)bufHiB << 32) | bufLoB;
    }
}

// ---------------------------------------------------------------------------
// Stage C: MFMA attention on spike bitmasks; emits ctx as bf16 hi/lo split.
// ---------------------------------------------------------------------------
#define ATT_C1 0.180336879f    // 0.125 * log2(e)
#define ATT_C2 11.541560327f   // 8 * log2(e)

__device__ inline short8v expand8(unsigned byte) {
    short8v r;
    #pragma unroll
    for (int e = 0; e < 8; e++)
        r[e] = (short)(((byte >> e) & 1u) ? 0x3F80 : 0);
    return r;
}

__device__ inline unsigned bfpk(float x, float y) {
    unsigned ux = __float_as_uint(x);
    unsigned uy = __float_as_uint(y);
    unsigned rx = (ux + 0x7FFFu + ((ux >> 16) & 1u)) >> 16;
    unsigned ry = (uy + 0x7FFFu + ((uy >> 16) & 1u)) >> 16;
    return rx | (ry << 16);
}

__global__ __launch_bounds__(256) void k_attn_mfma(
    const unsigned long long* __restrict__ masks,
    unsigned short* __restrict__ ctxh, unsigned short* __restrict__ ctxl)
{
    __shared__ __align__(16) unsigned short Klds[128][72];
    __shared__ __align__(16) unsigned short Vt[64][136];
    __shared__ unsigned long long vmbuf[2][128];

    const unsigned long long* qm_all = masks;
    const unsigned long long* km_all = masks + (size_t)64 * 1024;
    const unsigned long long* vm_all = masks + (size_t)2 * 64 * 1024;

    int n  = blockIdx.y;
    int qc = blockIdx.x;
    int tid = threadIdx.x;
    int wv = tid >> 6;
    int lane = tid & 63;
    int r15 = lane & 15, g = lane >> 4;

    const unsigned long long* km = km_all + (size_t)n * 1024;
    const unsigned long long* vm = vm_all + (size_t)n * 1024;

    unsigned long long qmask = qm_all[(size_t)n * 1024 + qc * 64 + wv * 16 + r15];
    short8v Qf[2];
    #pragma unroll
    for (int ch = 0; ch < 2; ch++)
        Qf[ch] = expand8((unsigned)(qmask >> ((ch * 4 + g) * 8)) & 0xFFu);

    f32x4 cx[4];
    #pragma unroll
    for (int mt = 0; mt < 4; mt++) cx[mt] = (f32x4){0.f, 0.f, 0.f, 0.f};
    float den = 0.f;

    if (tid < 128) vmbuf[0][tid] = vm[tid];
    __syncthreads();

    for (int kt = 0; kt < 8; kt++) {
        {
            int s = tid >> 1, half = tid & 1;
            unsigned long long m = km[kt * 128 + s];
            #pragma unroll
            for (int j = 0; j < 4; j++) {
                unsigned byte = (unsigned)(m >> (half * 32 + j * 8)) & 0xFFu;
                *reinterpret_cast<short8v*>(&Klds[s][(half * 4 + j) * 8]) = expand8(byte);
            }
        }
        {
            int dh = tid & 63;
            int sc4 = tid >> 6;
            #pragma unroll
            for (int j = 0; j < 4; j++) {
                short8v v2;
                #pragma unroll
                for (int e = 0; e < 8; e++) {
                    unsigned long long mv = vmbuf[kt & 1][sc4 * 32 + j * 8 + e];
                    v2[e] = (short)(((mv >> dh) & 1ull) ? 0x3F80 : 0);
                }
                *reinterpret_cast<short8v*>(&Vt[dh][(sc4 * 4 + j) * 8]) = v2;
            }
        }
        __syncthreads();

        if (tid < 128 && kt + 1 < 8) vmbuf[(kt + 1) & 1][tid] = vm[(kt + 1) * 128 + tid];

        f32x4 pf[8];
        #pragma unroll
        for (int mt = 0; mt < 8; mt++) {
            f32x4 c = (f32x4){0.f, 0.f, 0.f, 0.f};
            #pragma unroll
            for (int ch = 0; ch < 2; ch++) {
                short8v a = *reinterpret_cast<const short8v*>(&Klds[mt * 16 + r15][(ch * 4 + g) * 8]);
                c = __builtin_amdgcn_mfma_f32_16x16x32_bf16(a, Qf[ch], c, 0, 0, 0);
            }
            f32x4 p;
            #pragma unroll
            for (int i = 0; i < 4; i++) {
                p[i] = exp2f(c[i] * ATT_C1 - ATT_C2);
                den += p[i];
            }
            pf[mt] = p;
        }

        int src0 = ((g & 1) << 1) * 16 + r15;
        int src1 = src0 + 16;
        bool hi = (g >= 2);
        #pragma unroll
        for (int c4 = 0; c4 < 4; c4++) {
            unsigned d0 = bfpk(pf[2 * c4][0], pf[2 * c4][1]);
            unsigned d1 = bfpk(pf[2 * c4][2], pf[2 * c4][3]);
            unsigned d2 = bfpk(pf[2 * c4 + 1][0], pf[2 * c4 + 1][1]);
            unsigned d3 = bfpk(pf[2 * c4 + 1][2], pf[2 * c4 + 1][3]);
            unsigned a0 = __shfl((int)d0, src0), b0 = __shfl((int)d2, src0);
            unsigned a1 = __shfl((int)d1, src0), b1 = __shfl((int)d3, src0);
            unsigned a2 = __shfl((int)d0, src1), b2 = __shfl((int)d2, src1);
            unsigned a3 = __shfl((int)d1, src1), b3 = __shfl((int)d3, src1);
            union { unsigned u[4]; short8v s; } bw;
            bw.u[0] = hi ? b0 : a0;
            bw.u[1] = hi ? b1 : a1;
            bw.u[2] = hi ? b2 : a2;
            bw.u[3] = hi ? b3 : a3;
            #pragma unroll
            for (int mt = 0; mt < 4; mt++) {
                short8v a = *reinterpret_cast<const short8v*>(&Vt[mt * 16 + r15][(c4 * 4 + g) * 8]);
                cx[mt] = __builtin_amdgcn_mfma_f32_16x16x32_bf16(a, bw.s, cx[mt], 0, 0, 0);
            }
        }
        __syncthreads();
    }

    den += __shfl_xor(den, 16);
    den += __shfl_xor(den, 32);
    float inv = 1.f / den;

    int b = n >> 4, h = n & 15;
    int row = b * 1024 + qc * 64 + wv * 16 + r15;
    unsigned short* oph = ctxh + (size_t)row * 1024 + h * 64;
    unsigned short* opl = ctxl + (size_t)row * 1024 + h * 64;
    #pragma unroll
    for (int mt = 0; mt < 4; mt++)
        #pragma unroll
        for (int i = 0; i < 4; i++) {
            unsigned short hh, ll;
            bsplit(cx[mt][i] * inv, hh, ll);
            oph[mt * 16 + g * 4 + i] = hh;
            opl[mt * 16 + g * 4 + i] = ll;
        }
}

// ---------------------------------------------------------------------------
extern "C" void kernel_launch(void* const* d_in, const int* in_sizes, int n_in,
                              void* d_out, int out_size, void* d_ws, size_t ws_size,
                              hipStream_t stream) {
    const float* x    = (const float*)d_in[0];
    const float* Wq   = (const float*)d_in[1];
    const float* Wk   = (const float*)d_in[2];
    const float* Wv   = (const float*)d_in[3];
    const float* Wo   = (const float*)d_in[4];
    const float* bo   = (const float*)d_in[5];
    const float* Wqi  = (const float*)d_in[6];
    const float* Wqr  = (const float*)d_in[7];
    const float* Wki  = (const float*)d_in[8];
    const float* Wkr  = (const float*)d_in[9];
    const float* Wvi  = (const float*)d_in[10];
    const float* Wvr  = (const float*)d_in[11];
    const float* thq  = (const float*)d_in[12];
    const float* thk  = (const float*)d_in[13];
    const float* thv  = (const float*)d_in[14];

    char* ws = (char*)d_ws;
    float* cur = (float*)(ws + WS_CUR);
    unsigned short* xh  = (unsigned short*)(ws + WS_XH);
    unsigned short* xl  = (unsigned short*)(ws + WS_XL);
    unsigned short* wch = (unsigned short*)(ws + WS_WCH);
    unsigned short* wcl = (unsigned short*)(ws + WS_WCL);
    unsigned long long* masks = (unsigned long long*)(ws + WS_MSK);
    unsigned short* ctxh = (unsigned short*)(ws + WS_CTXH);
    unsigned short* ctxl = (unsigned short*)(ws + WS_CTXL);
    unsigned short* woh = (unsigned short*)(ws + WS_WOH);
    unsigned short* wol = (unsigned short*)(ws + WS_WOL);
    float* outp = (float*)d_out;

    k_prep<<<dim3(7168, 1, 1), 256, 0, stream>>>(x, Wq, Wk, Wv, Wqi, Wki, Wvi, xh, xl, wch, wcl);
    k_mfma_gemm<0><<<dim3(32, 8, 3), 512, 0, stream>>>(xh, xl, wch, wcl, cur, nullptr);
    k_lif_wo<<<dim3(608, 1, 1), 64, 0, stream>>>(cur, Wqr, Wkr, Wvr, thq, thk, thv, masks, Wo, woh, wol);
    k_attn_mfma<<<dim3(16, 64, 1), 256, 0, stream>>>(masks, ctxh, ctxl);
    k_mfma_gemm<1><<<dim3(32, 8, 1), 512, 0, stream>>>(ctxh, ctxl, woh, wol, outp, bo);
}

// Round 16
// 415.480 us; speedup vs baseline: 1.3499x; 1.3499x over previous
//
#include <hip/hip_runtime.h>
#include <hip/hip_bf16.h>

// Problem constants
#define B_  4
#define S_  1024
#define D_  1024
#define H_  16
#define DH_ 64
#define N_  64          // B*H
#define BS_ 4096        // B*S

// Workspace layout (bytes)
#define WS_CUR   0ull                        // 48 MB f32 cur[3][64][1024][64]
#define WS_XH    (WS_CUR + 48ull*1024*1024)  // 8 MB bf16 x_hi [4096][1024]
#define WS_XL    (WS_XH  +  8ull*1024*1024)  // 8 MB bf16 x_lo
#define WS_WCH   (WS_XL  +  8ull*1024*1024)  // 6 MB bf16 WcT_hi [3][1024][1024]
#define WS_WCL   (WS_WCH +  6ull*1024*1024)  // 6 MB bf16 WcT_lo
#define WS_MSK   (WS_WCL +  6ull*1024*1024)  // 1.5 MB masks
// overlays (safe by stream order):
#define WS_CTXH  WS_XH                       // attn output hi (x dead after proj)
#define WS_CTXL  WS_XL
#define WS_WOH   WS_WCH                      // Wo split (WcT dead after proj)
#define WS_WOL   (WS_WCH + 2ull*1024*1024)

typedef __attribute__((ext_vector_type(8))) short short8v;
typedef __attribute__((ext_vector_type(4))) float f32x4;

// round-to-nearest-even bf16 split: x == hi + lo + O(2^-18 |x|)
__device__ inline void bsplit(float x, unsigned short& h, unsigned short& l) {
    unsigned ux = __float_as_uint(x);
    unsigned rh = (ux + 0x7FFFu + ((ux >> 16) & 1u)) >> 16;
    h = (unsigned short)rh;
    float r = x - __uint_as_float(rh << 16);
    unsigned ur = __float_as_uint(r);
    l = (unsigned short)((ur + 0x7FFFu + ((ur >> 16) & 1u)) >> 16);
}

// ---------------------------------------------------------------------------
// k_prep: merged x-split (blocks 0..4095) + Wc transpose/split (4096..7167).
// ---------------------------------------------------------------------------
__global__ __launch_bounds__(256) void k_prep(
    const float* __restrict__ x,
    const float* __restrict__ Wq, const float* __restrict__ Wk, const float* __restrict__ Wv,
    const float* __restrict__ Wqi, const float* __restrict__ Wki, const float* __restrict__ Wvi,
    unsigned short* __restrict__ xh, unsigned short* __restrict__ xl,
    unsigned short* __restrict__ wch, unsigned short* __restrict__ wcl)
{
    int blk = blockIdx.x;
    int tid = threadIdx.x;

    if (blk < 4096) {
        int i = (blk * 256 + tid) * 4;
        float4 v = *reinterpret_cast<const float4*>(&x[i]);
        ushort4 h, l;
        bsplit(v.x, h.x, l.x);
        bsplit(v.y, h.y, l.y);
        bsplit(v.z, h.z, l.z);
        bsplit(v.w, h.w, l.w);
        *reinterpret_cast<ushort4*>(&xh[i]) = h;
        *reinterpret_cast<ushort4*>(&xl[i]) = l;
        return;
    }

    int q = blk - 4096;
    int z = q >> 10, hd = q & 1023;
    const float* W  = (z == 0) ? Wq  : (z == 1) ? Wk  : Wv;
    const float* Wi = (z == 0) ? Wqi : (z == 1) ? Wki : Wvi;
    int h = hd >> 6, d = hd & 63;

    __shared__ float ws[64];
    if (tid < 64) ws[tid] = Wi[d * 64 + tid];
    __syncthreads();

    const float* Wb = W + (size_t)h * 64 * 1024;
    float acc[4] = {0.f, 0.f, 0.f, 0.f};
    for (int j = 0; j < 64; j++) {
        float wv = ws[j];
        const float* row = Wb + (size_t)j * 1024;
        #pragma unroll
        for (int mi = 0; mi < 4; mi++)
            acc[mi] += row[tid + mi * 256] * wv;
    }
    unsigned short* oh = wch + (size_t)z * 1024 * 1024 + (size_t)hd * 1024;
    unsigned short* ol = wcl + (size_t)z * 1024 * 1024 + (size_t)hd * 1024;
    #pragma unroll
    for (int mi = 0; mi < 4; mi++) {
        unsigned short hh, ll;
        bsplit(acc[mi], hh, ll);
        oh[tid + mi * 256] = hh;
        ol[tid + mi * 256] = ll;
    }
}

// ---------------------------------------------------------------------------
// Split-bf16 MFMA GEMM: C[m][n] = sum_k A[m][k]*B[n][k]  (B n-major)
// v7: BK=32 SINGLE 32 KB buffer -> 4 blocks/CU (2x TLP vs v5's 64 KB) to
// cover the per-tile vmcnt(0) drain with cross-block overlap (the m97
// mechanism; intra-block pipelining regressed in rounds 8/14).
// Swizzle: stage slot p=l&3 holds global slot p^((l>>3)&3); read slot
// g^((r15>>1)&3) -> 8 distinct bank-quads per 8 rows, 2-way alias = free.
// K-chunk order ascending 32-wide = v5's order -> bit-identical output.
// ---------------------------------------------------------------------------
template<int OUT>
__global__ __launch_bounds__(512, 2) void k_mfma_gemm(
    const unsigned short* __restrict__ Ah, const unsigned short* __restrict__ Al,
    const unsigned short* __restrict__ Bh, const unsigned short* __restrict__ Bl,
    float* __restrict__ C, const float* __restrict__ bias)
{
    // 4 mats x 128 rows x 32 ushorts = 32 KB. mat m at m*4096 (ushorts).
    __shared__ __align__(16) unsigned short lds[4 * 128 * 32];

    int tid = threadIdx.x;
    int bx = blockIdx.x, by = blockIdx.y, bz = blockIdx.z;
    const unsigned short* Bhz = Bh + (size_t)bz * 1024 * 1024;
    const unsigned short* Blz = Bl + (size_t)bz * 1024 * 1024;
    int rb = bx * 128, cb = by * 128;

    int wid = tid >> 6, lane = tid & 63;
    int wr = wid >> 2, wc = wid & 3;          // 2x4 wave grid: 64-row x 32-col tiles
    int r15 = lane & 15, g = lane >> 4;

    // staging: 32 instrs/block = 4/wave; q = wid*4+i -> mat q>>3, 1KB chunk q&7
    int rowL = lane >> 2;                          // 0..15 row within chunk
    int gslot = (lane & 3) ^ ((lane >> 3) & 3);    // swizzled global k-slot
    int fx = (r15 >> 1) & 3;                       // read-side XOR

    f32x4 acc[4][2];
    #pragma unroll
    for (int mt = 0; mt < 4; mt++)
        #pragma unroll
        for (int nt = 0; nt < 2; nt++)
            acc[mt][nt] = (f32x4){0.f, 0.f, 0.f, 0.f};

    #pragma unroll 1
    for (int t = 0; t < 32; t++) {
        int kb = t * 32;
        #pragma unroll
        for (int i = 0; i < 4; i++) {
            int q = wid * 4 + i;
            int mat = q >> 3, ch = q & 7;
            const unsigned short* gsrc = (mat == 0) ? Ah : (mat == 1) ? Al
                                        : (mat == 2) ? Bhz : Blz;
            int rowoff = (mat < 2) ? rb : cb;
            int row = ch * 16 + rowL;
            __builtin_amdgcn_global_load_lds(
                (const __attribute__((address_space(1))) void*)
                    (gsrc + (size_t)(rowoff + row) * 1024 + kb + gslot * 8),
                (__attribute__((address_space(3))) void*)(&lds[mat * 4096 + ch * 512]),
                16, 0, 0);
        }
        __syncthreads();   // drains vmcnt -> tile resident

        short8v bh[2], bl[2];
        #pragma unroll
        for (int nt = 0; nt < 2; nt++) {
            int Crow = wc * 32 + nt * 16 + r15;
            int off = Crow * 32 + ((g ^ fx) * 8);
            bh[nt] = *reinterpret_cast<const short8v*>(&lds[2 * 4096 + off]);
            bl[nt] = *reinterpret_cast<const short8v*>(&lds[3 * 4096 + off]);
        }
        #pragma unroll
        for (int mt = 0; mt < 4; mt++) {
            int Arow = wr * 64 + mt * 16 + r15;
            int off = Arow * 32 + ((g ^ fx) * 8);
            short8v ah = *reinterpret_cast<const short8v*>(&lds[0 * 4096 + off]);
            short8v al = *reinterpret_cast<const short8v*>(&lds[1 * 4096 + off]);
            #pragma unroll
            for (int nt = 0; nt < 2; nt++) {
                acc[mt][nt] = __builtin_amdgcn_mfma_f32_16x16x32_bf16(bh[nt], ah, acc[mt][nt], 0, 0, 0);
                acc[mt][nt] = __builtin_amdgcn_mfma_f32_16x16x32_bf16(bl[nt], ah, acc[mt][nt], 0, 0, 0);
                acc[mt][nt] = __builtin_amdgcn_mfma_f32_16x16x32_bf16(bh[nt], al, acc[mt][nt], 0, 0, 0);
            }
        }
        __syncthreads();   // all waves done reading before next tile overwrites
    }

    if (OUT == 0) {
        float* out = C + (size_t)bz * 64 * 1024 * 64;
        int b = rb >> 10;
        #pragma unroll
        for (int nt = 0; nt < 2; nt++) {
            int col = cb + wc * 32 + nt * 16 + g * 4;   // hd base, 16B aligned
            int h = col >> 6, dd = col & 63;
            #pragma unroll
            for (int mt = 0; mt < 4; mt++) {
                int row = rb + wr * 64 + mt * 16 + r15; // b*1024 + s
                int s = row & 1023;
                f32x4 a = acc[mt][nt];
                *reinterpret_cast<float4*>(&out[(((size_t)(b * 16 + h)) * 1024 + s) * 64 + dd]) =
                    make_float4(a[0], a[1], a[2], a[3]);
            }
        }
    } else {
        #pragma unroll
        for (int nt = 0; nt < 2; nt++) {
            int col = cb + wc * 32 + nt * 16 + g * 4;
            float4 bv = *reinterpret_cast<const float4*>(&bias[col]);
            #pragma unroll
            for (int mt = 0; mt < 4; mt++) {
                int row = rb + wr * 64 + mt * 16 + r15;
                f32x4 a = acc[mt][nt];
                *reinterpret_cast<float4*>(&C[(size_t)row * 1024 + col]) =
                    make_float4(a[0] + bv.x, a[1] + bv.y, a[2] + bv.z, a[3] + bv.w);
            }
        }
    }
}

// ---------------------------------------------------------------------------
// Stage B: LIF scan (v3, proven 206 us) merged with Wo split — round-13
// version restored verbatim. Blocks 0..191: LIF. Blocks 192..703: Wo split.
// ---------------------------------------------------------------------------
__global__ __launch_bounds__(64) void k_lif_wo(
    const float* __restrict__ curAll,
    const float* __restrict__ Wrq, const float* __restrict__ Wrk, const float* __restrict__ Wrv,
    const float* __restrict__ thq, const float* __restrict__ thk, const float* __restrict__ thv,
    unsigned long long* __restrict__ masks,
    const float* __restrict__ Wo, unsigned short* __restrict__ woh, unsigned short* __restrict__ wol)
{
    __shared__ float T[16 * 16 * 64];    // T[g][nib][d], 64 KB
    __shared__ __align__(16) float cbuf[2][64 * 64];   // 2 x 16 KB batch buffers

    int bid = blockIdx.x;
    int d = threadIdx.x;

    if (bid >= 192) {
        int q = bid - 192;
        #pragma unroll
        for (int it = 0; it < 8; it++) {
            int i = q * 2048 + it * 256 + d * 4;
            float4 v = *reinterpret_cast<const float4*>(&Wo[i]);
            ushort4 h, l;
            bsplit(v.x, h.x, l.x);
            bsplit(v.y, h.y, l.y);
            bsplit(v.z, h.z, l.z);
            bsplit(v.w, h.w, l.w);
            *reinterpret_cast<ushort4*>(&woh[i]) = h;
            *reinterpret_cast<ushort4*>(&wol[i]) = l;
        }
        return;
    }

    int l = bid >> 6, n = bid & 63;
    const float* W  = (l == 0) ? Wrq : (l == 1) ? Wrk : Wrv;
    const float* th = (l == 0) ? thq : (l == 1) ? thk : thv;
    const float* cbase = curAll + (((size_t)l * 64 + n) * 1024) * 64;
    unsigned long long* mout = masks + ((size_t)l * 64 + n) * 1024;

    #pragma unroll
    for (int j = 0; j < 16; j++)
        __builtin_amdgcn_global_load_lds(
            (const __attribute__((address_space(1))) void*)(cbase + j * 256 + d * 4),
            (__attribute__((address_space(3))) void*)(&cbuf[0][j * 256]), 16, 0, 0);

    float theta = th[d];

    for (int g = 0; g < 16; g++) {
        float w0 = W[d * 64 + 4 * g + 0];
        float w1 = W[d * 64 + 4 * g + 1];
        float w2 = W[d * 64 + 4 * g + 2];
        float w3 = W[d * 64 + 4 * g + 3];
        #pragma unroll
        for (int c = 0; c < 16; c++) {
            float t = 0.f;
            if (c & 1) t += w0;
            if (c & 2) t += w1;
            if (c & 4) t += w2;
            if (c & 8) t += w3;
            T[g * 1024 + c * 64 + d] = t;
        }
    }
    __syncthreads();

    float v = 0.f, refrac = 0.f, athr = 1.0f;
    unsigned mlo = 0u, mhi = 0u;
    unsigned bufLo = 0u, bufHi = 0u;

    for (int b = 0; b < 16; b++) {
        if (b < 15) {
            const float* src = cbase + (size_t)(b + 1) * 4096;
            float* dst = cbuf[(b + 1) & 1];
            #pragma unroll
            for (int j = 0; j < 16; j++)
                __builtin_amdgcn_global_load_lds(
                    (const __attribute__((address_space(1))) void*)(src + j * 256 + d * 4),
                    (__attribute__((address_space(3))) void*)(dst + j * 256), 16, 0, 0);
        }
        if (b == 0)      asm volatile("s_waitcnt vmcnt(16)" ::: "memory");
        else if (b < 15) asm volatile("s_waitcnt vmcnt(17)" ::: "memory");
        else             asm volatile("s_waitcnt vmcnt(0)"  ::: "memory");

        const float* cb = cbuf[b & 1];
        #pragma unroll 8
        for (int i = 0; i < 64; i++) {
            float curv = cb[i * 64 + d];

            float t[16];
            #pragma unroll
            for (int g = 0; g < 8; g++)
                t[g] = T[g * 1024 + (int)(((mlo >> (4 * g)) & 15u) << 6) + d];
            #pragma unroll
            for (int g = 0; g < 8; g++)
                t[8 + g] = T[(8 + g) * 1024 + (int)(((mhi >> (4 * g)) & 15u) << 6) + d];

            #pragma unroll
            for (int k = 8; k >= 1; k >>= 1)
                #pragma unroll
                for (int j = 0; j < k; j++)
                    t[j] = t[j] + t[j + k];
            float total = curv + t[0];

            v = 0.9f * v + total;
            v = (refrac <= 0.f) ? v : 0.f;
            bool sp = (v >= athr);
            unsigned long long m = __ballot(sp);
            mlo = (unsigned)m;
            mhi = (unsigned)(m >> 32);
            bufLo = (d == i) ? mlo : bufLo;
            bufHi = (d == i) ? mhi : bufHi;
            float sm = sp ? 1.f : 0.f;
            v = sp ? 0.f : v;
            refrac = fmaxf(refrac - 1.f, sm * 2.f);
            athr = 0.95f * athr + sm * theta;
        }
        mout[b * 64 + d] = ((unsigned long long)bufHi << 32) | bufLo;
    }
}

// ---------------------------------------------------------------------------
// Stage C: MFMA attention on spike bitmasks; emits ctx as bf16 hi/lo split.
// ---------------------------------------------------------------------------
#define ATT_C1 0.180336879f    // 0.125 * log2(e)
#define ATT_C2 11.541560327f   // 8 * log2(e)

__device__ inline short8v expand8(unsigned byte) {
    short8v r;
    #pragma unroll
    for (int e = 0; e < 8; e++)
        r[e] = (short)(((byte >> e) & 1u) ? 0x3F80 : 0);
    return r;
}

__device__ inline unsigned bfpk(float x, float y) {
    unsigned ux = __float_as_uint(x);
    unsigned uy = __float_as_uint(y);
    unsigned rx = (ux + 0x7FFFu + ((ux >> 16) & 1u)) >> 16;
    unsigned ry = (uy + 0x7FFFu + ((uy >> 16) & 1u)) >> 16;
    return rx | (ry << 16);
}

__global__ __launch_bounds__(256) void k_attn_mfma(
    const unsigned long long* __restrict__ masks,
    unsigned short* __restrict__ ctxh, unsigned short* __restrict__ ctxl)
{
    __shared__ __align__(16) unsigned short Klds[128][72];
    __shared__ __align__(16) unsigned short Vt[64][136];
    __shared__ unsigned long long vmbuf[2][128];

    const unsigned long long* qm_all = masks;
    const unsigned long long* km_all = masks + (size_t)64 * 1024;
    const unsigned long long* vm_all = masks + (size_t)2 * 64 * 1024;

    int n  = blockIdx.y;
    int qc = blockIdx.x;
    int tid = threadIdx.x;
    int wv = tid >> 6;
    int lane = tid & 63;
    int r15 = lane & 15, g = lane >> 4;

    const unsigned long long* km = km_all + (size_t)n * 1024;
    const unsigned long long* vm = vm_all + (size_t)n * 1024;

    unsigned long long qmask = qm_all[(size_t)n * 1024 + qc * 64 + wv * 16 + r15];
    short8v Qf[2];
    #pragma unroll
    for (int ch = 0; ch < 2; ch++)
        Qf[ch] = expand8((unsigned)(qmask >> ((ch * 4 + g) * 8)) & 0xFFu);

    f32x4 cx[4];
    #pragma unroll
    for (int mt = 0; mt < 4; mt++) cx[mt] = (f32x4){0.f, 0.f, 0.f, 0.f};
    float den = 0.f;

    if (tid < 128) vmbuf[0][tid] = vm[tid];
    __syncthreads();

    for (int kt = 0; kt < 8; kt++) {
        {
            int s = tid >> 1, half = tid & 1;
            unsigned long long m = km[kt * 128 + s];
            #pragma unroll
            for (int j = 0; j < 4; j++) {
                unsigned byte = (unsigned)(m >> (half * 32 + j * 8)) & 0xFFu;
                *reinterpret_cast<short8v*>(&Klds[s][(half * 4 + j) * 8]) = expand8(byte);
            }
        }
        {
            int dh = tid & 63;
            int sc4 = tid >> 6;
            #pragma unroll
            for (int j = 0; j < 4; j++) {
                short8v v2;
                #pragma unroll
                for (int e = 0; e < 8; e++) {
                    unsigned long long mv = vmbuf[kt & 1][sc4 * 32 + j * 8 + e];
                    v2[e] = (short)(((mv >> dh) & 1ull) ? 0x3F80 : 0);
                }
                *reinterpret_cast<short8v*>(&Vt[dh][(sc4 * 4 + j) * 8]) = v2;
            }
        }
        __syncthreads();

        if (tid < 128 && kt + 1 < 8) vmbuf[(kt + 1) & 1][tid] = vm[(kt + 1) * 128 + tid];

        f32x4 pf[8];
        #pragma unroll
        for (int mt = 0; mt < 8; mt++) {
            f32x4 c = (f32x4){0.f, 0.f, 0.f, 0.f};
            #pragma unroll
            for (int ch = 0; ch < 2; ch++) {
                short8v a = *reinterpret_cast<const short8v*>(&Klds[mt * 16 + r15][(ch * 4 + g) * 8]);
                c = __builtin_amdgcn_mfma_f32_16x16x32_bf16(a, Qf[ch], c, 0, 0, 0);
            }
            f32x4 p;
            #pragma unroll
            for (int i = 0; i < 4; i++) {
                p[i] = exp2f(c[i] * ATT_C1 - ATT_C2);
                den += p[i];
            }
            pf[mt] = p;
        }

        int src0 = ((g & 1) << 1) * 16 + r15;
        int src1 = src0 + 16;
        bool hi = (g >= 2);
        #pragma unroll
        for (int c4 = 0; c4 < 4; c4++) {
            unsigned d0 = bfpk(pf[2 * c4][0], pf[2 * c4][1]);
            unsigned d1 = bfpk(pf[2 * c4][2], pf[2 * c4][3]);
            unsigned d2 = bfpk(pf[2 * c4 + 1][0], pf[2 * c4 + 1][1]);
            unsigned d3 = bfpk(pf[2 * c4 + 1][2], pf[2 * c4 + 1][3]);
            unsigned a0 = __shfl((int)d0, src0), b0 = __shfl((int)d2, src0);
            unsigned a1 = __shfl((int)d1, src0), b1 = __shfl((int)d3, src0);
            unsigned a2 = __shfl((int)d0, src1), b2 = __shfl((int)d2, src1);
            unsigned a3 = __shfl((int)d1, src1), b3 = __shfl((int)d3, src1);
            union { unsigned u[4]; short8v s; } bw;
            bw.u[0] = hi ? b0 : a0;
            bw.u[1] = hi ? b1 : a1;
            bw.u[2] = hi ? b2 : a2;
            bw.u[3] = hi ? b3 : a3;
            #pragma unroll
            for (int mt = 0; mt < 4; mt++) {
                short8v a = *reinterpret_cast<const short8v*>(&Vt[mt * 16 + r15][(c4 * 4 + g) * 8]);
                cx[mt] = __builtin_amdgcn_mfma_f32_16x16x32_bf16(a, bw.s, cx[mt], 0, 0, 0);
            }
        }
        __syncthreads();
    }

    den += __shfl_xor(den, 16);
    den += __shfl_xor(den, 32);
    float inv = 1.f / den;

    int b = n >> 4, h = n & 15;
    int row = b * 1024 + qc * 64 + wv * 16 + r15;
    unsigned short* oph = ctxh + (size_t)row * 1024 + h * 64;
    unsigned short* opl = ctxl + (size_t)row * 1024 + h * 64;
    #pragma unroll
    for (int mt = 0; mt < 4; mt++)
        #pragma unroll
        for (int i = 0; i < 4; i++) {
            unsigned short hh, ll;
            bsplit(cx[mt][i] * inv, hh, ll);
            oph[mt * 16 + g * 4 + i] = hh;
            opl[mt * 16 + g * 4 + i] = ll;
        }
}

// ---------------------------------------------------------------------------
extern "C" void kernel_launch(void* const* d_in, const int* in_sizes, int n_in,
                              void* d_out, int out_size, void* d_ws, size_t ws_size,
                              hipStream_t stream) {
    const float* x    = (const float*)d_in[0];
    const float* Wq   = (const float*)d_in[1];
    const float* Wk   = (const float*)d_in[2];
    const float* Wv   = (const float*)d_in[3];
    const float* Wo   = (const float*)d_in[4];
    const float* bo   = (const float*)d_in[5];
    const float* Wqi  = (const float*)d_in[6];
    const float* Wqr  = (const float*)d_in[7];
    const float* Wki  = (const float*)d_in[8];
    const float* Wkr  = (const float*)d_in[9];
    const float* Wvi  = (const float*)d_in[10];
    const float* Wvr  = (const float*)d_in[11];
    const float* thq  = (const float*)d_in[12];
    const float* thk  = (const float*)d_in[13];
    const float* thv  = (const float*)d_in[14];

    char* ws = (char*)d_ws;
    float* cur = (float*)(ws + WS_CUR);
    unsigned short* xh  = (unsigned short*)(ws + WS_XH);
    unsigned short* xl  = (unsigned short*)(ws + WS_XL);
    unsigned short* wch = (unsigned short*)(ws + WS_WCH);
    unsigned short* wcl = (unsigned short*)(ws + WS_WCL);
    unsigned long long* masks = (unsigned long long*)(ws + WS_MSK);
    unsigned short* ctxh = (unsigned short*)(ws + WS_CTXH);
    unsigned short* ctxl = (unsigned short*)(ws + WS_CTXL);
    unsigned short* woh = (unsigned short*)(ws + WS_WOH);
    unsigned short* wol = (unsigned short*)(ws + WS_WOL);
    float* outp = (float*)d_out;

    k_prep<<<dim3(7168, 1, 1), 256, 0, stream>>>(x, Wq, Wk, Wv, Wqi, Wki, Wvi, xh, xl, wch, wcl);
    k_mfma_gemm<0><<<dim3(32, 8, 3), 512, 0, stream>>>(xh, xl, wch, wcl, cur, nullptr);
    k_lif_wo<<<dim3(704, 1, 1), 64, 0, stream>>>(cur, Wqr, Wkr, Wvr, thq, thk, thv, masks, Wo, woh, wol);
    k_attn_mfma<<<dim3(16, 64, 1), 256, 0, stream>>>(masks, ctxh, ctxl);
    k_mfma_gemm<1><<<dim3(32, 8, 1), 512, 0, stream>>>(ctxh, ctxl, woh, wol, outp, bo);
}

// Round 17
// 385.445 us; speedup vs baseline: 1.4550x; 1.0779x over previous
//
#include <hip/hip_runtime.h>
#include <hip/hip_bf16.h>

// Problem constants
#define B_  4
#define S_  1024
#define D_  1024
#define H_  16
#define DH_ 64
#define N_  64          // B*H
#define BS_ 4096        // B*S

// Workspace layout (bytes)
#define WS_CUR   0ull                        // 48 MB f32 cur[3][64][1024][64]
#define WS_XH    (WS_CUR + 48ull*1024*1024)  // 8 MB bf16 x_hi [4096][1024]
#define WS_XL    (WS_XH  +  8ull*1024*1024)  // 8 MB bf16 x_lo
#define WS_WCH   (WS_XL  +  8ull*1024*1024)  // 6 MB bf16 WcT_hi [3][1024][1024]
#define WS_WCL   (WS_WCH +  6ull*1024*1024)  // 6 MB bf16 WcT_lo
#define WS_MSK   (WS_WCL +  6ull*1024*1024)  // 1.5 MB masks
// overlays (safe by stream order):
#define WS_CTXH  WS_XH                       // attn output hi (x dead after proj)
#define WS_CTXL  WS_XL
#define WS_WOH   WS_WCH                      // Wo split (WcT dead after proj)
#define WS_WOL   (WS_WCH + 2ull*1024*1024)

typedef __attribute__((ext_vector_type(8))) short short8v;
typedef __attribute__((ext_vector_type(4))) float f32x4;

// round-to-nearest-even bf16 split: x == hi + lo + O(2^-18 |x|)
__device__ inline void bsplit(float x, unsigned short& h, unsigned short& l) {
    unsigned ux = __float_as_uint(x);
    unsigned rh = (ux + 0x7FFFu + ((ux >> 16) & 1u)) >> 16;
    h = (unsigned short)rh;
    float r = x - __uint_as_float(rh << 16);
    unsigned ur = __float_as_uint(r);
    l = (unsigned short)((ur + 0x7FFFu + ((ur >> 16) & 1u)) >> 16);
}

// ---------------------------------------------------------------------------
// k_prep: merged x-split (blocks 0..4095) + Wc transpose/split (4096..4863).
// wc branch v2: block per (z, h, m-chunk of 64). The 16 KB W-chunk and 16 KB
// Wi are staged to LDS ONCE per block (old version re-read the 256 KB slab
// 1024x per z through L2/L3). j-ascending W*Wi order -> bit-identical Wc.
// ---------------------------------------------------------------------------
__global__ __launch_bounds__(256) void k_prep(
    const float* __restrict__ x,
    const float* __restrict__ Wq, const float* __restrict__ Wk, const float* __restrict__ Wv,
    const float* __restrict__ Wqi, const float* __restrict__ Wki, const float* __restrict__ Wvi,
    unsigned short* __restrict__ xh, unsigned short* __restrict__ xl,
    unsigned short* __restrict__ wch, unsigned short* __restrict__ wcl)
{
    __shared__ float ws2[64 * 65];                     // Wi[d][j], +1 pad
    __shared__ __align__(16) float wrow[64 * 64];      // W[j][m-local]

    int blk = blockIdx.x;
    int tid = threadIdx.x;

    if (blk < 4096) {
        // ---- x -> bf16 hi/lo split
        int i = (blk * 256 + tid) * 4;
        float4 v = *reinterpret_cast<const float4*>(&x[i]);
        ushort4 h, l;
        bsplit(v.x, h.x, l.x);
        bsplit(v.y, h.y, l.y);
        bsplit(v.z, h.z, l.z);
        bsplit(v.w, h.w, l.w);
        *reinterpret_cast<ushort4*>(&xh[i]) = h;
        *reinterpret_cast<ushort4*>(&xl[i]) = l;
        return;
    }

    // ---- WcT[z][h*64+d][m] = sum_j W_z[h*64+j][m] * Wi_z[d][j]
    int q = blk - 4096;                 // 0..767
    int z = q >> 8, rem = q & 255;
    int h = rem >> 4, mc = rem & 15;    // m-chunk of 64
    const float* W  = (z == 0) ? Wq  : (z == 1) ? Wk  : Wv;
    const float* Wi = (z == 0) ? Wqi : (z == 1) ? Wki : Wvi;

    int td = tid >> 2, tq = tid & 3;    // td: j (stage) / d (compute); tq: 16-col group

    // stage Wi[d=td][j] -> ws2[td*65+j]  (padded: bank (d+j)%32, conflict-free)
    #pragma unroll
    for (int c = 0; c < 4; c++) {
        float4 v = *reinterpret_cast<const float4*>(&Wi[td * 64 + tq * 16 + c * 4]);
        int o = td * 65 + tq * 16 + c * 4;
        ws2[o] = v.x; ws2[o + 1] = v.y; ws2[o + 2] = v.z; ws2[o + 3] = v.w;
    }
    // stage W[h*64+j=td][mc*64 + 0..63] -> wrow[td*64 + ...]
    {
        const float* Wb = W + ((size_t)(h * 64 + td)) * 1024 + mc * 64;
        #pragma unroll
        for (int c = 0; c < 4; c++) {
            float4 v = *reinterpret_cast<const float4*>(&Wb[tq * 16 + c * 4]);
            *reinterpret_cast<float4*>(&wrow[td * 64 + tq * 16 + c * 4]) = v;
        }
    }
    __syncthreads();

    float acc[16];
    #pragma unroll
    for (int i = 0; i < 16; i++) acc[i] = 0.f;
    for (int j = 0; j < 64; j++) {
        float wv = ws2[td * 65 + j];
        #pragma unroll
        for (int c = 0; c < 4; c++) {
            float4 r = *reinterpret_cast<const float4*>(&wrow[j * 64 + tq * 16 + c * 4]);
            acc[c * 4 + 0] += r.x * wv;
            acc[c * 4 + 1] += r.y * wv;
            acc[c * 4 + 2] += r.z * wv;
            acc[c * 4 + 3] += r.w * wv;
        }
    }

    int hd = h * 64 + td;
    size_t obase = (size_t)z * 1024 * 1024 + (size_t)hd * 1024 + mc * 64 + tq * 16;
    #pragma unroll
    for (int c = 0; c < 4; c++) {
        ushort4 hv, lv;
        bsplit(acc[c * 4 + 0], hv.x, lv.x);
        bsplit(acc[c * 4 + 1], hv.y, lv.y);
        bsplit(acc[c * 4 + 2], hv.z, lv.z);
        bsplit(acc[c * 4 + 3], hv.w, lv.w);
        *reinterpret_cast<ushort4*>(&wch[obase + c * 4]) = hv;
        *reinterpret_cast<ushort4*>(&wcl[obase + c * 4]) = lv;
    }
}

// ---------------------------------------------------------------------------
// Split-bf16 MFMA GEMM: C[m][n] = sum_k A[m][k]*B[n][k]  (B n-major)
// v5 (proven rounds 10/13, best measured): global_load_lds staging, BK=64,
// single 64 KB buffer, XOR-swizzled global source + same XOR on ds_read,
// float4 epilogue. (v6 pipelined and v7 BK=32 both regressed — reverted.)
// ---------------------------------------------------------------------------
template<int OUT>
__global__ __launch_bounds__(512, 4) void k_mfma_gemm(
    const unsigned short* __restrict__ Ah, const unsigned short* __restrict__ Al,
    const unsigned short* __restrict__ Bh, const unsigned short* __restrict__ Bl,
    float* __restrict__ C, const float* __restrict__ bias)
{
    // 4 mats x 128 rows x 64 ushorts = 64 KB. mat m at m*8192 (ushorts).
    __shared__ __align__(16) unsigned short lds[4 * 128 * 64];

    int tid = threadIdx.x;
    int bx = blockIdx.x, by = blockIdx.y, bz = blockIdx.z;
    const unsigned short* Bhz = Bh + (size_t)bz * 1024 * 1024;
    const unsigned short* Blz = Bl + (size_t)bz * 1024 * 1024;
    int rb = bx * 128, cb = by * 128;

    int wid = tid >> 6, lane = tid & 63;
    int wr = wid >> 2, wc = wid & 3;          // 2x4 wave grid: 64-row x 32-col tiles
    int r15 = lane & 15, g = lane >> 4;

    int rowA = lane >> 3;          // 0..7, == row&7 within chunk
    int kpsw = ((lane & 7) ^ rowA) * 8;

    f32x4 acc[4][2];
    #pragma unroll
    for (int mt = 0; mt < 4; mt++)
        #pragma unroll
        for (int nt = 0; nt < 2; nt++)
            acc[mt][nt] = (f32x4){0.f, 0.f, 0.f, 0.f};

    #pragma unroll 1
    for (int t = 0; t < 16; t++) {
        int kb = t * 64;
        #pragma unroll
        for (int i = 0; i < 8; i++) {
            int q = wid * 8 + i;
            int mat = q >> 4, ch = q & 15;
            const unsigned short* gsrc = (mat == 0) ? Ah : (mat == 1) ? Al
                                        : (mat == 2) ? Bhz : Blz;
            int rowoff = (mat < 2) ? rb : cb;
            int row = ch * 8 + rowA;
            __builtin_amdgcn_global_load_lds(
                (const __attribute__((address_space(1))) void*)
                    (gsrc + (size_t)(rowoff + row) * 1024 + kb + kpsw),
                (__attribute__((address_space(3))) void*)(&lds[mat * 8192 + ch * 512]),
                16, 0, 0);
        }
        __syncthreads();   // drains vmcnt -> tile resident

        #pragma unroll
        for (int kk = 0; kk < 2; kk++) {
            short8v bh[2], bl[2];
            #pragma unroll
            for (int nt = 0; nt < 2; nt++) {
                int Crow = wc * 32 + nt * 16 + r15;
                int off = Crow * 64 + (((kk * 4 + g) ^ (Crow & 7)) * 8);
                bh[nt] = *reinterpret_cast<const short8v*>(&lds[2 * 8192 + off]);
                bl[nt] = *reinterpret_cast<const short8v*>(&lds[3 * 8192 + off]);
            }
            #pragma unroll
            for (int mt = 0; mt < 4; mt++) {
                int Arow = wr * 64 + mt * 16 + r15;
                int off = Arow * 64 + (((kk * 4 + g) ^ (Arow & 7)) * 8);
                short8v ah = *reinterpret_cast<const short8v*>(&lds[0 * 8192 + off]);
                short8v al = *reinterpret_cast<const short8v*>(&lds[1 * 8192 + off]);
                #pragma unroll
                for (int nt = 0; nt < 2; nt++) {
                    acc[mt][nt] = __builtin_amdgcn_mfma_f32_16x16x32_bf16(bh[nt], ah, acc[mt][nt], 0, 0, 0);
                    acc[mt][nt] = __builtin_amdgcn_mfma_f32_16x16x32_bf16(bl[nt], ah, acc[mt][nt], 0, 0, 0);
                    acc[mt][nt] = __builtin_amdgcn_mfma_f32_16x16x32_bf16(bh[nt], al, acc[mt][nt], 0, 0, 0);
                }
            }
        }
        __syncthreads();   // all waves done reading before next stage overwrites
    }

    if (OUT == 0) {
        float* out = C + (size_t)bz * 64 * 1024 * 64;
        int b = rb >> 10;
        #pragma unroll
        for (int nt = 0; nt < 2; nt++) {
            int col = cb + wc * 32 + nt * 16 + g * 4;   // hd base, 16B aligned
            int h = col >> 6, dd = col & 63;
            #pragma unroll
            for (int mt = 0; mt < 4; mt++) {
                int row = rb + wr * 64 + mt * 16 + r15; // b*1024 + s
                int s = row & 1023;
                f32x4 a = acc[mt][nt];
                *reinterpret_cast<float4*>(&out[(((size_t)(b * 16 + h)) * 1024 + s) * 64 + dd]) =
                    make_float4(a[0], a[1], a[2], a[3]);
            }
        }
    } else {
        #pragma unroll
        for (int nt = 0; nt < 2; nt++) {
            int col = cb + wc * 32 + nt * 16 + g * 4;
            float4 bv = *reinterpret_cast<const float4*>(&bias[col]);
            #pragma unroll
            for (int mt = 0; mt < 4; mt++) {
                int row = rb + wr * 64 + mt * 16 + r15;
                f32x4 a = acc[mt][nt];
                *reinterpret_cast<float4*>(&C[(size_t)row * 1024 + col]) =
                    make_float4(a[0] + bv.x, a[1] + bv.y, a[2] + bv.z, a[3] + bv.w);
            }
        }
    }
}

// ---------------------------------------------------------------------------
// Stage B: LIF scan (v3, proven 206 us) merged with Wo split.
// Blocks 0..191: LIF. Blocks 192..703: Wo -> bf16 hi/lo split (hidden).
// ---------------------------------------------------------------------------
__global__ __launch_bounds__(64) void k_lif_wo(
    const float* __restrict__ curAll,
    const float* __restrict__ Wrq, const float* __restrict__ Wrk, const float* __restrict__ Wrv,
    const float* __restrict__ thq, const float* __restrict__ thk, const float* __restrict__ thv,
    unsigned long long* __restrict__ masks,
    const float* __restrict__ Wo, unsigned short* __restrict__ woh, unsigned short* __restrict__ wol)
{
    __shared__ float T[16 * 16 * 64];    // T[g][nib][d], 64 KB
    __shared__ __align__(16) float cbuf[2][64 * 64];   // 2 x 16 KB batch buffers

    int bid = blockIdx.x;
    int d = threadIdx.x;

    if (bid >= 192) {
        int q = bid - 192;
        #pragma unroll
        for (int it = 0; it < 8; it++) {
            int i = q * 2048 + it * 256 + d * 4;
            float4 v = *reinterpret_cast<const float4*>(&Wo[i]);
            ushort4 h, l;
            bsplit(v.x, h.x, l.x);
            bsplit(v.y, h.y, l.y);
            bsplit(v.z, h.z, l.z);
            bsplit(v.w, h.w, l.w);
            *reinterpret_cast<ushort4*>(&woh[i]) = h;
            *reinterpret_cast<ushort4*>(&wol[i]) = l;
        }
        return;
    }

    int l = bid >> 6, n = bid & 63;
    const float* W  = (l == 0) ? Wrq : (l == 1) ? Wrk : Wrv;
    const float* th = (l == 0) ? thq : (l == 1) ? thk : thv;
    const float* cbase = curAll + (((size_t)l * 64 + n) * 1024) * 64;
    unsigned long long* mout = masks + ((size_t)l * 64 + n) * 1024;

    #pragma unroll
    for (int j = 0; j < 16; j++)
        __builtin_amdgcn_global_load_lds(
            (const __attribute__((address_space(1))) void*)(cbase + j * 256 + d * 4),
            (__attribute__((address_space(3))) void*)(&cbuf[0][j * 256]), 16, 0, 0);

    float theta = th[d];

    for (int g = 0; g < 16; g++) {
        float w0 = W[d * 64 + 4 * g + 0];
        float w1 = W[d * 64 + 4 * g + 1];
        float w2 = W[d * 64 + 4 * g + 2];
        float w3 = W[d * 64 + 4 * g + 3];
        #pragma unroll
        for (int c = 0; c < 16; c++) {
            float t = 0.f;
            if (c & 1) t += w0;
            if (c & 2) t += w1;
            if (c & 4) t += w2;
            if (c & 8) t += w3;
            T[g * 1024 + c * 64 + d] = t;
        }
    }
    __syncthreads();

    float v = 0.f, refrac = 0.f, athr = 1.0f;
    unsigned mlo = 0u, mhi = 0u;
    unsigned bufLo = 0u, bufHi = 0u;

    for (int b = 0; b < 16; b++) {
        if (b < 15) {
            const float* src = cbase + (size_t)(b + 1) * 4096;
            float* dst = cbuf[(b + 1) & 1];
            #pragma unroll
            for (int j = 0; j < 16; j++)
                __builtin_amdgcn_global_load_lds(
                    (const __attribute__((address_space(1))) void*)(src + j * 256 + d * 4),
                    (__attribute__((address_space(3))) void*)(dst + j * 256), 16, 0, 0);
        }
        if (b == 0)      asm volatile("s_waitcnt vmcnt(16)" ::: "memory");
        else if (b < 15) asm volatile("s_waitcnt vmcnt(17)" ::: "memory");
        else             asm volatile("s_waitcnt vmcnt(0)"  ::: "memory");

        const float* cb = cbuf[b & 1];
        #pragma unroll 8
        for (int i = 0; i < 64; i++) {
            float curv = cb[i * 64 + d];

            float t[16];
            #pragma unroll
            for (int g = 0; g < 8; g++)
                t[g] = T[g * 1024 + (int)(((mlo >> (4 * g)) & 15u) << 6) + d];
            #pragma unroll
            for (int g = 0; g < 8; g++)
                t[8 + g] = T[(8 + g) * 1024 + (int)(((mhi >> (4 * g)) & 15u) << 6) + d];

            #pragma unroll
            for (int k = 8; k >= 1; k >>= 1)
                #pragma unroll
                for (int j = 0; j < k; j++)
                    t[j] = t[j] + t[j + k];
            float total = curv + t[0];

            v = 0.9f * v + total;
            v = (refrac <= 0.f) ? v : 0.f;
            bool sp = (v >= athr);
            unsigned long long m = __ballot(sp);
            mlo = (unsigned)m;
            mhi = (unsigned)(m >> 32);
            bufLo = (d == i) ? mlo : bufLo;
            bufHi = (d == i) ? mhi : bufHi;
            float sm = sp ? 1.f : 0.f;
            v = sp ? 0.f : v;
            refrac = fmaxf(refrac - 1.f, sm * 2.f);
            athr = 0.95f * athr + sm * theta;
        }
        mout[b * 64 + d] = ((unsigned long long)bufHi << 32) | bufLo;
    }
}

// ---------------------------------------------------------------------------
// Stage C: MFMA attention on spike bitmasks; emits ctx as bf16 hi/lo split.
// ---------------------------------------------------------------------------
#define ATT_C1 0.180336879f    // 0.125 * log2(e)
#define ATT_C2 11.541560327f   // 8 * log2(e)

__device__ inline short8v expand8(unsigned byte) {
    short8v r;
    #pragma unroll
    for (int e = 0; e < 8; e++)
        r[e] = (short)(((byte >> e) & 1u) ? 0x3F80 : 0);
    return r;
}

__device__ inline unsigned bfpk(float x, float y) {
    unsigned ux = __float_as_uint(x);
    unsigned uy = __float_as_uint(y);
    unsigned rx = (ux + 0x7FFFu + ((ux >> 16) & 1u)) >> 16;
    unsigned ry = (uy + 0x7FFFu + ((uy >> 16) & 1u)) >> 16;
    return rx | (ry << 16);
}

__global__ __launch_bounds__(256) void k_attn_mfma(
    const unsigned long long* __restrict__ masks,
    unsigned short* __restrict__ ctxh, unsigned short* __restrict__ ctxl)
{
    __shared__ __align__(16) unsigned short Klds[128][72];
    __shared__ __align__(16) unsigned short Vt[64][136];
    __shared__ unsigned long long vmbuf[2][128];

    const unsigned long long* qm_all = masks;
    const unsigned long long* km_all = masks + (size_t)64 * 1024;
    const unsigned long long* vm_all = masks + (size_t)2 * 64 * 1024;

    int n  = blockIdx.y;
    int qc = blockIdx.x;
    int tid = threadIdx.x;
    int wv = tid >> 6;
    int lane = tid & 63;
    int r15 = lane & 15, g = lane >> 4;

    const unsigned long long* km = km_all + (size_t)n * 1024;
    const unsigned long long* vm = vm_all + (size_t)n * 1024;

    unsigned long long qmask = qm_all[(size_t)n * 1024 + qc * 64 + wv * 16 + r15];
    short8v Qf[2];
    #pragma unroll
    for (int ch = 0; ch < 2; ch++)
        Qf[ch] = expand8((unsigned)(qmask >> ((ch * 4 + g) * 8)) & 0xFFu);

    f32x4 cx[4];
    #pragma unroll
    for (int mt = 0; mt < 4; mt++) cx[mt] = (f32x4){0.f, 0.f, 0.f, 0.f};
    float den = 0.f;

    if (tid < 128) vmbuf[0][tid] = vm[tid];
    __syncthreads();

    for (int kt = 0; kt < 8; kt++) {
        {
            int s = tid >> 1, half = tid & 1;
            unsigned long long m = km[kt * 128 + s];
            #pragma unroll
            for (int j = 0; j < 4; j++) {
                unsigned byte = (unsigned)(m >> (half * 32 + j * 8)) & 0xFFu;
                *reinterpret_cast<short8v*>(&Klds[s][(half * 4 + j) * 8]) = expand8(byte);
            }
        }
        {
            int dh = tid & 63;
            int sc4 = tid >> 6;
            #pragma unroll
            for (int j = 0; j < 4; j++) {
                short8v v2;
                #pragma unroll
                for (int e = 0; e < 8; e++) {
                    unsigned long long mv = vmbuf[kt & 1][sc4 * 32 + j * 8 + e];
                    v2[e] = (short)(((mv >> dh) & 1ull) ? 0x3F80 : 0);
                }
                *reinterpret_cast<short8v*>(&Vt[dh][(sc4 * 4 + j) * 8]) = v2;
            }
        }
        __syncthreads();

        if (tid < 128 && kt + 1 < 8) vmbuf[(kt + 1) & 1][tid] = vm[(kt + 1) * 128 + tid];

        f32x4 pf[8];
        #pragma unroll
        for (int mt = 0; mt < 8; mt++) {
            f32x4 c = (f32x4){0.f, 0.f, 0.f, 0.f};
            #pragma unroll
            for (int ch = 0; ch < 2; ch++) {
                short8v a = *reinterpret_cast<const short8v*>(&Klds[mt * 16 + r15][(ch * 4 + g) * 8]);
                c = __builtin_amdgcn_mfma_f32_16x16x32_bf16(a, Qf[ch], c, 0, 0, 0);
            }
            f32x4 p;
            #pragma unroll
            for (int i = 0; i < 4; i++) {
                p[i] = exp2f(c[i] * ATT_C1 - ATT_C2);
                den += p[i];
            }
            pf[mt] = p;
        }

        int src0 = ((g & 1) << 1) * 16 + r15;
        int src1 = src0 + 16;
        bool hi = (g >= 2);
        #pragma unroll
        for (int c4 = 0; c4 < 4; c4++) {
            unsigned d0 = bfpk(pf[2 * c4][0], pf[2 * c4][1]);
            unsigned d1 = bfpk(pf[2 * c4][2], pf[2 * c4][3]);
            unsigned d2 = bfpk(pf[2 * c4 + 1][0], pf[2 * c4 + 1][1]);
            unsigned d3 = bfpk(pf[2 * c4 + 1][2], pf[2 * c4 + 1][3]);
            unsigned a0 = __shfl((int)d0, src0), b0 = __shfl((int)d2, src0);
            unsigned a1 = __shfl((int)d1, src0), b1 = __shfl((int)d3, src0);
            unsigned a2 = __shfl((int)d0, src1), b2 = __shfl((int)d2, src1);
            unsigned a3 = __shfl((int)d1, src1), b3 = __shfl((int)d3, src1);
            union { unsigned u[4]; short8v s; } bw;
            bw.u[0] = hi ? b0 : a0;
            bw.u[1] = hi ? b1 : a1;
            bw.u[2] = hi ? b2 : a2;
            bw.u[3] = hi ? b3 : a3;
            #pragma unroll
            for (int mt = 0; mt < 4; mt++) {
                short8v a = *reinterpret_cast<const short8v*>(&Vt[mt * 16 + r15][(c4 * 4 + g) * 8]);
                cx[mt] = __builtin_amdgcn_mfma_f32_16x16x32_bf16(a, bw.s, cx[mt], 0, 0, 0);
            }
        }
        __syncthreads();
    }

    den += __shfl_xor(den, 16);
    den += __shfl_xor(den, 32);
    float inv = 1.f / den;

    int b = n >> 4, h = n & 15;
    int row = b * 1024 + qc * 64 + wv * 16 + r15;
    unsigned short* oph = ctxh + (size_t)row * 1024 + h * 64;
    unsigned short* opl = ctxl + (size_t)row * 1024 + h * 64;
    #pragma unroll
    for (int mt = 0; mt < 4; mt++)
        #pragma unroll
        for (int i = 0; i < 4; i++) {
            unsigned short hh, ll;
            bsplit(cx[mt][i] * inv, hh, ll);
            oph[mt * 16 + g * 4 + i] = hh;
            opl[mt * 16 + g * 4 + i] = ll;
        }
}

// ---------------------------------------------------------------------------
extern "C" void kernel_launch(void* const* d_in, const int* in_sizes, int n_in,
                              void* d_out, int out_size, void* d_ws, size_t ws_size,
                              hipStream_t stream) {
    const float* x    = (const float*)d_in[0];
    const float* Wq   = (const float*)d_in[1];
    const float* Wk   = (const float*)d_in[2];
    const float* Wv   = (const float*)d_in[3];
    const float* Wo   = (const float*)d_in[4];
    const float* bo   = (const float*)d_in[5];
    const float* Wqi  = (const float*)d_in[6];
    const float* Wqr  = (const float*)d_in[7];
    const float* Wki  = (const float*)d_in[8];
    const float* Wkr  = (const float*)d_in[9];
    const float* Wvi  = (const float*)d_in[10];
    const float* Wvr  = (const float*)d_in[11];
    const float* thq  = (const float*)d_in[12];
    const float* thk  = (const float*)d_in[13];
    const float* thv  = (const float*)d_in[14];

    char* ws = (char*)d_ws;
    float* cur = (float*)(ws + WS_CUR);
    unsigned short* xh  = (unsigned short*)(ws + WS_XH);
    unsigned short* xl  = (unsigned short*)(ws + WS_XL);
    unsigned short* wch = (unsigned short*)(ws + WS_WCH);
    unsigned short* wcl = (unsigned short*)(ws + WS_WCL);
    unsigned long long* masks = (unsigned long long*)(ws + WS_MSK);
    unsigned short* ctxh = (unsigned short*)(ws + WS_CTXH);
    unsigned short* ctxl = (unsigned short*)(ws + WS_CTXL);
    unsigned short* woh = (unsigned short*)(ws + WS_WOH);
    unsigned short* wol = (unsigned short*)(ws + WS_WOL);
    float* outp = (float*)d_out;

    k_prep<<<dim3(4864, 1, 1), 256, 0, stream>>>(x, Wq, Wk, Wv, Wqi, Wki, Wvi, xh, xl, wch, wcl);
    k_mfma_gemm<0><<<dim3(32, 8, 3), 512, 0, stream>>>(xh, xl, wch, wcl, cur, nullptr);
    k_lif_wo<<<dim3(704, 1, 1), 64, 0, stream>>>(cur, Wqr, Wkr, Wvr, thq, thk, thv, masks, Wo, woh, wol);
    k_attn_mfma<<<dim3(16, 64, 1), 256, 0, stream>>>(masks, ctxh, ctxl);
    k_mfma_gemm<1><<<dim3(32, 8, 1), 512, 0, stream>>>(ctxh, ctxl, woh, wol, outp, bo);
}